// Round 9
// baseline (137.513 us; speedup 1.0000x reference)
//
#include <hip/hip_runtime.h>
#include <math.h>

// SSAaligner: s[i,j] = -sum_d |x[i,d]-y[j,d]|, x from z_x(D,N), y from z_y(D,M)
// a = softmax_rows(s), b = softmax_cols(s), u = a+b-a*b, out = sum(u*s)/sum(u)
// D=256, N=M=1024. fp32 in, fp32 scalar out.
//
// R9: scompute was ~2.4x LDS-issue-bound (per wave-d: x b128 + y b64 = ~19
// LDS cyc vs 16 VALU instr). Now thread tile = 4r x 4c (32 VALU per wave-d,
// one y b128 + one x broadcast b128) with a d-split x2 to keep 512 blocks =
// 2 blocks/CU. Stats can't fold over partial d, so a lean sumstats pass reads
// the two 4 MB slabs and emits row stats + col partials; colcombine folds
// 512 stripes; final re-reads slabs, ticket-divides. ~40 us of total is the
// harness's 268 MB ws-poison fill (untouchable).

#define DD 256
#define NN 1024
#define NQ 256         // float4 per row
#define HD 128         // d's per half

__device__ __forceinline__ float waveMax(float v) {
  #pragma unroll
  for (int off = 32; off; off >>= 1) v = fmaxf(v, __shfl_xor(v, off, 64));
  return v;
}
__device__ __forceinline__ float waveSum(float v) {
  #pragma unroll
  for (int off = 32; off; off >>= 1) v += __shfl_xor(v, off, 64);
  return v;
}
__device__ __forceinline__ float blockMax(float v, float* red) {
  v = waveMax(v);
  __syncthreads();
  if ((threadIdx.x & 63) == 0) red[threadIdx.x >> 6] = v;
  __syncthreads();
  return fmaxf(fmaxf(red[0], red[1]), fmaxf(red[2], red[3]));
}
__device__ __forceinline__ float blockSum(float v, float* red) {
  v = waveSum(v);
  __syncthreads();
  if ((threadIdx.x & 63) == 0) red[threadIdx.x >> 6] = v;
  __syncthreads();
  return red[0] + red[1] + red[2] + red[3];
}

// ---------------- fast path ----------------

// Grid (4 j-chunks, 64 i-tiles, 2 d-halves) = 512 blocks, 256 thr, 2 blk/CU.
// Tile 16r x 256c x 128d. Wave w owns rows i0+4w..+3 (x = one b128 broadcast
// per d); lane ln owns cols j0+4ln..+3 (y = one b128 per d). 16 acc/thread.
__global__ __launch_bounds__(256, 2)
void scompute_kernel(const float* __restrict__ zx, const float* __restrict__ zy,
                     float* __restrict__ Sp) {
  const int bx = blockIdx.x;        // j-chunk 0..3 (256 cols)
  const int by = blockIdx.y;        // i-tile 0..63 (16 rows)
  const int h  = blockIdx.z;        // d-half 0..1
  const int i0 = by * 16;
  const int t  = threadIdx.x;
  const int w  = t >> 6;            // wave 0..3
  const int ln = t & 63;            // lane = col-quad

  __shared__ float xs[HD][16];      // 8 KB, xs[d][r] — wave-uniform broadcast
  __shared__ float ys[2][8][256];   // 16 KB, double-buffered 8-d y chunks

  const float4* __restrict__ X4 = (const float4*)zx;
  const float4* __restrict__ Y4 = (const float4*)zy;

  // stage x half-slab: 128 d x 4 quads = 512 float4, 2 per thread
  #pragma unroll
  for (int i = 0; i < 2; ++i) {
    const int k = t + i * 256;
    const int d = k >> 2, rq = k & 3;
    *(float4*)&xs[d][rq * 4] = X4[(h * HD + d) * NQ + by * 4 + rq];
  }

  // stage y chunk 0: 8 d x 64 quads = 512 float4, 2 per thread
  const int sd = t >> 5;            // d-row 0..7
  const int sq = t & 31;            // quad 0..31 (plus +32)
  const int jq0 = bx * 64;
  *(float4*)&ys[0][sd][sq * 4]        = Y4[(h * HD + sd) * NQ + jq0 + sq];
  *(float4*)&ys[0][sd][(sq + 32) * 4] = Y4[(h * HD + sd) * NQ + jq0 + sq + 32];
  __syncthreads();

  float acc[4][4];
  #pragma unroll
  for (int r = 0; r < 4; ++r)
    #pragma unroll
    for (int c = 0; c < 4; ++c) acc[r][c] = 0.f;

  #pragma unroll 1
  for (int n = 0; n < HD / 8; ++n) {
    const int buf = n & 1;
    float4 p0, p1;
    if (n < HD / 8 - 1) {
      p0 = Y4[(h * HD + 8 * (n + 1) + sd) * NQ + jq0 + sq];
      p1 = Y4[(h * HD + 8 * (n + 1) + sd) * NQ + jq0 + sq + 32];
    }
    #pragma unroll
    for (int dd = 0; dd < 8; ++dd) {
      const int d = n * 8 + dd;
      const float4 xv = *(const float4*)&xs[d][w * 4];
      const float4 yv = *(const float4*)&ys[buf][dd][ln * 4];
      acc[0][0] += fabsf(xv.x - yv.x); acc[0][1] += fabsf(xv.x - yv.y);
      acc[0][2] += fabsf(xv.x - yv.z); acc[0][3] += fabsf(xv.x - yv.w);
      acc[1][0] += fabsf(xv.y - yv.x); acc[1][1] += fabsf(xv.y - yv.y);
      acc[1][2] += fabsf(xv.y - yv.z); acc[1][3] += fabsf(xv.y - yv.w);
      acc[2][0] += fabsf(xv.z - yv.x); acc[2][1] += fabsf(xv.z - yv.y);
      acc[2][2] += fabsf(xv.z - yv.z); acc[2][3] += fabsf(xv.z - yv.w);
      acc[3][0] += fabsf(xv.w - yv.x); acc[3][1] += fabsf(xv.w - yv.y);
      acc[3][2] += fabsf(xv.w - yv.z); acc[3][3] += fabsf(xv.w - yv.w);
    }
    if (n < HD / 8 - 1) {
      *(float4*)&ys[buf ^ 1][sd][sq * 4]        = p0;
      *(float4*)&ys[buf ^ 1][sd][(sq + 32) * 4] = p1;
    }
    __syncthreads();
  }

  float4* __restrict__ S4 = (float4*)Sp + (size_t)h * (NN * NQ);
  #pragma unroll
  for (int r = 0; r < 4; ++r)
    S4[(i0 + w * 4 + r) * NQ + jq0 + ln] =
        make_float4(acc[r][0], acc[r][1], acc[r][2], acc[r][3]);
}

// 512 blocks x 2 rows: v = slab0 + slab1 (no write-back), full row stats,
// per-2-row-stripe col partials.
__global__ __launch_bounds__(256)
void sumstats_kernel(const float* __restrict__ Sp,
                     float* __restrict__ rmax, float* __restrict__ rsum,
                     float* __restrict__ pm, float* __restrict__ ps) {
  __shared__ float red[4];
  const int t = threadIdx.x;
  const int row0 = blockIdx.x * 2;
  const float4* A = (const float4*)Sp;
  const float4* B = A + (size_t)NN * NQ;
  float4 v[2];
  #pragma unroll
  for (int r = 0; r < 2; ++r) {
    const float4 a = A[(row0 + r) * NQ + t];
    const float4 b = B[(row0 + r) * NQ + t];
    v[r] = make_float4(a.x + b.x, a.y + b.y, a.z + b.z, a.w + b.w);
  }
  #pragma unroll
  for (int r = 0; r < 2; ++r) {
    float m = fmaxf(fmaxf(-v[r].x, -v[r].y), fmaxf(-v[r].z, -v[r].w));
    m = blockMax(m, red);
    float l = __expf(-v[r].x - m) + __expf(-v[r].y - m) +
              __expf(-v[r].z - m) + __expf(-v[r].w - m);
    l = blockSum(l, red);
    if (t == 0) { rmax[row0 + r] = m; rsum[row0 + r] = l; }
  }
  float4 cm, cl;
  cm.x = fmaxf(-v[0].x, -v[1].x); cm.y = fmaxf(-v[0].y, -v[1].y);
  cm.z = fmaxf(-v[0].z, -v[1].z); cm.w = fmaxf(-v[0].w, -v[1].w);
  cl.x = __expf(-v[0].x - cm.x) + __expf(-v[1].x - cm.x);
  cl.y = __expf(-v[0].y - cm.y) + __expf(-v[1].y - cm.y);
  cl.z = __expf(-v[0].z - cm.z) + __expf(-v[1].z - cm.z);
  cl.w = __expf(-v[0].w - cm.w) + __expf(-v[1].w - cm.w);
  ((float4*)pm)[blockIdx.x * NQ + t] = cm;
  ((float4*)ps)[blockIdx.x * NQ + t] = cl;
}

// 16 blocks: fold the 512 col-stripes. 4 groups x 128 stripes, LDS-merged.
__global__ __launch_bounds__(256)
void colcombine_kernel(const float* __restrict__ pm, const float* __restrict__ ps,
                       float* __restrict__ cmax, float* __restrict__ csum,
                       float* __restrict__ accum) {
  __shared__ float sm[4][64], sl[4][64];
  const int b = blockIdx.x, t = threadIdx.x;
  if (b == 0 && t == 0) {
    accum[0] = 0.f; accum[1] = 0.f; ((unsigned int*)accum)[2] = 0u;
  }
  const int c = t & 63;
  const int g = t >> 6;
  const int j = b * 64 + c;
  float m = -1e30f;
  #pragma unroll 8
  for (int k = 0; k < 128; ++k) m = fmaxf(m, pm[(g * 128 + k) * NN + j]);
  float l = 0.f;
  #pragma unroll 8
  for (int k = 0; k < 128; ++k)
    l += __expf(pm[(g * 128 + k) * NN + j] - m) * ps[(g * 128 + k) * NN + j];
  sm[g][c] = m; sl[g][c] = l;
  __syncthreads();
  if (g == 0) {
    const float m0 = sm[0][c], m1 = sm[1][c], m2 = sm[2][c], m3 = sm[3][c];
    const float M = fmaxf(fmaxf(m0, m1), fmaxf(m2, m3));
    const float L = sl[0][c] * __expf(m0 - M) + sl[1][c] * __expf(m1 - M) +
                    sl[2][c] * __expf(m2 - M) + sl[3][c] * __expf(m3 - M);
    cmax[j] = M; csum[j] = L;
  }
}

// 512 blocks x 2 rows: v = slab0+slab1, u = a+b-a*b, reduce, atomic;
// LAST block divides.
__global__ __launch_bounds__(256)
void final_kernel(const float* __restrict__ Sp,
                  const float* __restrict__ rmax, const float* __restrict__ rsum,
                  const float* __restrict__ cmax, const float* __restrict__ csum,
                  float* __restrict__ accum, float* __restrict__ out) {
  __shared__ float redn[4], redd[4];
  const int t = threadIdx.x;
  const int row0 = blockIdx.x * 2;
  const float4* A = (const float4*)Sp;
  const float4* B = A + (size_t)NN * NQ;
  const float4 cm = ((const float4*)cmax)[t];
  const float4 cs = ((const float4*)csum)[t];
  float un = 0.f, ud = 0.f;
  #pragma unroll
  for (int r = 0; r < 2; ++r) {
    const int row = row0 + r;
    const float rm = rmax[row];
    const float ri = 1.f / rsum[row];
    const float4 pa = A[row * NQ + t];
    const float4 pb = B[row * NQ + t];
    const float4 p = make_float4(pa.x + pb.x, pa.y + pb.y, pa.z + pb.z, pa.w + pb.w);
    {
      const float s = -p.x;
      const float a = __expf(s - rm) * ri;
      const float b = __expf(s - cm.x) / cs.x;
      const float u = a + b - a * b;
      un += u * s; ud += u;
    }
    {
      const float s = -p.y;
      const float a = __expf(s - rm) * ri;
      const float b = __expf(s - cm.y) / cs.y;
      const float u = a + b - a * b;
      un += u * s; ud += u;
    }
    {
      const float s = -p.z;
      const float a = __expf(s - rm) * ri;
      const float b = __expf(s - cm.z) / cs.z;
      const float u = a + b - a * b;
      un += u * s; ud += u;
    }
    {
      const float s = -p.w;
      const float a = __expf(s - rm) * ri;
      const float b = __expf(s - cm.w) / cs.w;
      const float u = a + b - a * b;
      un += u * s; ud += u;
    }
  }
  un = waveSum(un); ud = waveSum(ud);
  if ((t & 63) == 0) { redn[t >> 6] = un; redd[t >> 6] = ud; }
  __syncthreads();
  if (t == 0) {
    atomicAdd(&accum[0], redn[0] + redn[1] + redn[2] + redn[3]);
    atomicAdd(&accum[1], redd[0] + redd[1] + redd[2] + redd[3]);
    __threadfence();
    unsigned int* cnt = (unsigned int*)accum + 2;
    const unsigned int old = atomicAdd(cnt, 1u);
    if (old == gridDim.x - 1) {
      const float n = atomicAdd(&accum[0], 0.f);
      const float d = atomicAdd(&accum[1], 0.f);
      out[0] = n / d;
    }
  }
}

// ---------------- fallback path (R2, ws >= ~148 KB, proven) ----------------

#define TJ  128
#define NCH (NN / TJ)
#define BLK 256

__global__ __launch_bounds__(BLK)
void stats2_kernel(const float* __restrict__ zx, const float* __restrict__ zy,
                   float* __restrict__ partM, float* __restrict__ partS) {
  const int side = blockIdx.z;
  const float* __restrict__ X = side ? zy : zx;
  const float* __restrict__ Y = side ? zx : zy;
  const int j0 = blockIdx.x * TJ;
  const int i0 = blockIdx.y * 8;
  const int t  = threadIdx.x;
  const int rg = t >> 5;
  const int c  = t & 31;

  __shared__ float xs[8 * DD];
  for (int k = t; k < 8 * DD; k += BLK)
    xs[k] = X[(k >> 3) * NN + i0 + (k & 7)];
  __syncthreads();

  const float4* __restrict__ Y4 = (const float4*)Y;
  const int yb = (j0 >> 2) + c;
  float4 acc = make_float4(0.f, 0.f, 0.f, 0.f);
  #pragma unroll 8
  for (int d = 0; d < DD; ++d) {
    const float4 yv = Y4[d * NQ + yb];
    const float xv = xs[d * 8 + rg];
    acc.x += fabsf(xv - yv.x);
    acc.y += fabsf(xv - yv.y);
    acc.z += fabsf(xv - yv.z);
    acc.w += fabsf(xv - yv.w);
  }

  float m = fmaxf(fmaxf(-acc.x, -acc.y), fmaxf(-acc.z, -acc.w));
  #pragma unroll
  for (int off = 16; off > 0; off >>= 1) m = fmaxf(m, __shfl_xor(m, off, 32));
  float p = __expf(-acc.x - m) + __expf(-acc.y - m) +
            __expf(-acc.z - m) + __expf(-acc.w - m);
  #pragma unroll
  for (int off = 16; off > 0; off >>= 1) p += __shfl_xor(p, off, 32);

  if (c == 0) {
    const int idx = side * (NCH * NN) + blockIdx.x * NN + (i0 + rg);
    partM[idx] = m;
    partS[idx] = p;
  }
}

__global__ __launch_bounds__(BLK)
void combine_kernel_fb(const float* __restrict__ partM, const float* __restrict__ partS,
                       float* __restrict__ rmax, float* __restrict__ rsum,
                       float* __restrict__ cmax, float* __restrict__ csum,
                       float* __restrict__ accum) {
  const int gid = blockIdx.x * BLK + threadIdx.x;
  if (gid == 0) { accum[0] = 0.f; accum[1] = 0.f; }
  const int sd = gid >> 10;
  const int i  = gid & (NN - 1);
  float mk[NCH], sk[NCH];
  #pragma unroll
  for (int k = 0; k < NCH; ++k) {
    mk[k] = partM[sd * (NCH * NN) + k * NN + i];
    sk[k] = partS[sd * (NCH * NN) + k * NN + i];
  }
  float m = mk[0];
  #pragma unroll
  for (int k = 1; k < NCH; ++k) m = fmaxf(m, mk[k]);
  float s = 0.f;
  #pragma unroll
  for (int k = 0; k < NCH; ++k) s += __expf(mk[k] - m) * sk[k];
  if (sd == 0) { rmax[i] = m; rsum[i] = s; }
  else         { cmax[i] = m; csum[i] = s; }
}

__global__ __launch_bounds__(BLK)
void final2_kernel(const float* __restrict__ zx, const float* __restrict__ zy,
                   const float* __restrict__ rmax, const float* __restrict__ rsum,
                   const float* __restrict__ cmax, const float* __restrict__ csum,
                   float* __restrict__ accum) {
  const int j0 = blockIdx.x * TJ;
  const int i0 = blockIdx.y * 8;
  const int t  = threadIdx.x;
  const int rg = t >> 5;
  const int c  = t & 31;

  __shared__ float xs[8 * DD];
  __shared__ float redn[4], redd[4];
  for (int k = t; k < 8 * DD; k += BLK)
    xs[k] = zx[(k >> 3) * NN + i0 + (k & 7)];
  __syncthreads();

  const float4* __restrict__ Y4 = (const float4*)zy;
  const int yb = (j0 >> 2) + c;
  float4 acc = make_float4(0.f, 0.f, 0.f, 0.f);
  #pragma unroll 8
  for (int d = 0; d < DD; ++d) {
    const float4 yv = Y4[d * NQ + yb];
    const float xv = xs[d * 8 + rg];
    acc.x += fabsf(xv - yv.x);
    acc.y += fabsf(xv - yv.y);
    acc.z += fabsf(xv - yv.z);
    acc.w += fabsf(xv - yv.w);
  }

  const int i = i0 + rg;
  const float rm = rmax[i];
  const float ri = 1.f / rsum[i];
  const float4 cm = ((const float4*)cmax)[yb];
  const float4 cs = ((const float4*)csum)[yb];

  float un = 0.f, ud = 0.f;
  {
    const float s = -acc.x;
    const float a = __expf(s - rm) * ri;
    const float b = __expf(s - cm.x) / cs.x;
    const float u = a + b - a * b;
    un += u * s; ud += u;
  }
  {
    const float s = -acc.y;
    const float a = __expf(s - rm) * ri;
    const float b = __expf(s - cm.y) / cs.y;
    const float u = a + b - a * b;
    un += u * s; ud += u;
  }
  {
    const float s = -acc.z;
    const float a = __expf(s - rm) * ri;
    const float b = __expf(s - cm.z) / cs.z;
    const float u = a + b - a * b;
    un += u * s; ud += u;
  }
  {
    const float s = -acc.w;
    const float a = __expf(s - rm) * ri;
    const float b = __expf(s - cm.w) / cs.w;
    const float u = a + b - a * b;
    un += u * s; ud += u;
  }

  un = waveSum(un); ud = waveSum(ud);
  if ((t & 63) == 0) { redn[t >> 6] = un; redd[t >> 6] = ud; }
  __syncthreads();
  if (t == 0) {
    atomicAdd(&accum[0], redn[0] + redn[1] + redn[2] + redn[3]);
    atomicAdd(&accum[1], redd[0] + redd[1] + redd[2] + redd[3]);
  }
}

__global__ void finalize_kernel(const float* __restrict__ accum, float* __restrict__ out) {
  out[0] = accum[0] / accum[1];
}

// ---------------------------------------------------------------------------

extern "C" void kernel_launch(void* const* d_in, const int* in_sizes, int n_in,
                              void* d_out, int out_size, void* d_ws, size_t ws_size,
                              hipStream_t stream) {
  const float* zx = (const float*)d_in[0];   // (1, D, N): X[d*N + i]
  const float* zy = (const float*)d_in[1];   // (1, D, M): Y[d*M + j]
  float* ws  = (float*)d_ws;
  float* out = (float*)d_out;

  // fast-path ws layout (floats): ~12.6 MB
  float* accum = ws;                         // [0]=num, [1]=den, [2]=ticket
  float* Sp    = ws + 16;                    // 2 slabs x 1M floats (8 MB)
  float* pm    = Sp + 2 * NN * NN;           // 512 * 1024
  float* ps    = pm + 512 * NN;              // 512 * 1024
  float* rmax  = ps + 512 * NN;
  float* rsum  = rmax + NN;
  float* cmax  = rsum + NN;
  float* csum  = cmax + NN;
  const size_t need = (size_t)((csum + NN) - ws) * sizeof(float);

  if (ws_size >= need) {
    dim3 g1(4, 64, 2);                       // 512 blocks
    scompute_kernel<<<g1, 256, 0, stream>>>(zx, zy, Sp);
    sumstats_kernel<<<NN / 2, 256, 0, stream>>>(Sp, rmax, rsum, pm, ps);
    colcombine_kernel<<<16, 256, 0, stream>>>(pm, ps, cmax, csum, accum);
    final_kernel<<<NN / 2, 256, 0, stream>>>(Sp, rmax, rsum, cmax, csum, accum, out);
  } else {
    // R2 fallback (~148 KB)
    float* partM = ws + 16;
    float* partS = partM + 2 * NCH * NN;
    float* frmax = partS + 2 * NCH * NN;
    float* frsum = frmax + NN;
    float* fcmax = frsum + NN;
    float* fcsum = fcmax + NN;
    dim3 sgrid(NCH, NN / 8, 2);
    stats2_kernel<<<sgrid, BLK, 0, stream>>>(zx, zy, partM, partS);
    combine_kernel_fb<<<(2 * NN) / BLK, BLK, 0, stream>>>(partM, partS,
                                                          frmax, frsum, fcmax, fcsum, accum);
    dim3 fgrid(NCH, NN / 8);
    final2_kernel<<<fgrid, BLK, 0, stream>>>(zx, zy, frmax, frsum, fcmax, fcsum, accum);
    finalize_kernel<<<1, 1, 0, stream>>>(accum, out);
  }
}

// Round 10
// 118.123 us; speedup vs baseline: 1.1642x; 1.1642x over previous
//
#include <hip/hip_runtime.h>
#include <math.h>

// SSAaligner: s[i,j] = -sum_d |x[i,d]-y[j,d]|, x from z_x(D,N), y from z_y(D,M)
// a = softmax_rows(s), b = softmax_cols(s), u = a+b-a*b, out = sum(u*s)/sum(u)
// D=256, N=M=1024. fp32 in, fp32 scalar out.
//
// R10: keep R9's scompute (d-split x2, 4r x 4c, 2 b128 LDS reads per wave-d
// serving 32 MACs -- best reads-per-MAC config; ds_read cost is ~fixed per
// instruction). R9's +32us regression was downstream: colcombine's 16-block
// stride-4KB fold (latency tail) and sumstats' 8-barrier block reductions.
// Now: sumstats = wave-per-row (no barriers for row stats, 1 barrier for col
// merge, 256 blocks); colcombine = 32 blocks, j-fastest coalesced fold.
// ~41 us of total is the harness's 268 MB ws-poison fill (untouchable).

#define DD 256
#define NN 1024
#define NQ 256         // float4 per row
#define HD 128         // d's per half

__device__ __forceinline__ float waveMax(float v) {
  #pragma unroll
  for (int off = 32; off; off >>= 1) v = fmaxf(v, __shfl_xor(v, off, 64));
  return v;
}
__device__ __forceinline__ float waveSum(float v) {
  #pragma unroll
  for (int off = 32; off; off >>= 1) v += __shfl_xor(v, off, 64);
  return v;
}

// ---------------- fast path ----------------

// Grid (4 j-chunks, 64 i-tiles, 2 d-halves) = 512 blocks, 256 thr, 2 blk/CU.
// Tile 16r x 256c x 128d. Wave w owns rows i0+4w..+3 (x = one b128 broadcast
// per d); lane ln owns cols j0+4ln..+3 (y = one b128 per d). 16 acc/thread.
__global__ __launch_bounds__(256, 2)
void scompute_kernel(const float* __restrict__ zx, const float* __restrict__ zy,
                     float* __restrict__ Sp) {
  const int bx = blockIdx.x;        // j-chunk 0..3 (256 cols)
  const int by = blockIdx.y;        // i-tile 0..63 (16 rows)
  const int h  = blockIdx.z;        // d-half 0..1
  const int i0 = by * 16;
  const int t  = threadIdx.x;
  const int w  = t >> 6;            // wave 0..3
  const int ln = t & 63;            // lane = col-quad

  __shared__ float xs[HD][16];      // 8 KB, xs[d][r] — wave-uniform broadcast
  __shared__ float ys[2][8][256];   // 16 KB, double-buffered 8-d y chunks

  const float4* __restrict__ X4 = (const float4*)zx;
  const float4* __restrict__ Y4 = (const float4*)zy;

  // stage x half-slab: 128 d x 4 quads = 512 float4, 2 per thread
  #pragma unroll
  for (int i = 0; i < 2; ++i) {
    const int k = t + i * 256;
    const int d = k >> 2, rq = k & 3;
    *(float4*)&xs[d][rq * 4] = X4[(h * HD + d) * NQ + by * 4 + rq];
  }

  // stage y chunk 0: 8 d x 64 quads = 512 float4, 2 per thread
  const int sd = t >> 5;            // d-row 0..7
  const int sq = t & 31;            // quad 0..31 (plus +32)
  const int jq0 = bx * 64;
  *(float4*)&ys[0][sd][sq * 4]        = Y4[(h * HD + sd) * NQ + jq0 + sq];
  *(float4*)&ys[0][sd][(sq + 32) * 4] = Y4[(h * HD + sd) * NQ + jq0 + sq + 32];
  __syncthreads();

  float acc[4][4];
  #pragma unroll
  for (int r = 0; r < 4; ++r)
    #pragma unroll
    for (int c = 0; c < 4; ++c) acc[r][c] = 0.f;

  #pragma unroll 1
  for (int n = 0; n < HD / 8; ++n) {
    const int buf = n & 1;
    float4 p0, p1;
    if (n < HD / 8 - 1) {
      p0 = Y4[(h * HD + 8 * (n + 1) + sd) * NQ + jq0 + sq];
      p1 = Y4[(h * HD + 8 * (n + 1) + sd) * NQ + jq0 + sq + 32];
    }
    #pragma unroll
    for (int dd = 0; dd < 8; ++dd) {
      const int d = n * 8 + dd;
      const float4 xv = *(const float4*)&xs[d][w * 4];
      const float4 yv = *(const float4*)&ys[buf][dd][ln * 4];
      acc[0][0] += fabsf(xv.x - yv.x); acc[0][1] += fabsf(xv.x - yv.y);
      acc[0][2] += fabsf(xv.x - yv.z); acc[0][3] += fabsf(xv.x - yv.w);
      acc[1][0] += fabsf(xv.y - yv.x); acc[1][1] += fabsf(xv.y - yv.y);
      acc[1][2] += fabsf(xv.y - yv.z); acc[1][3] += fabsf(xv.y - yv.w);
      acc[2][0] += fabsf(xv.z - yv.x); acc[2][1] += fabsf(xv.z - yv.y);
      acc[2][2] += fabsf(xv.z - yv.z); acc[2][3] += fabsf(xv.z - yv.w);
      acc[3][0] += fabsf(xv.w - yv.x); acc[3][1] += fabsf(xv.w - yv.y);
      acc[3][2] += fabsf(xv.w - yv.z); acc[3][3] += fabsf(xv.w - yv.w);
    }
    if (n < HD / 8 - 1) {
      *(float4*)&ys[buf ^ 1][sd][sq * 4]        = p0;
      *(float4*)&ys[buf ^ 1][sd][(sq + 32) * 4] = p1;
    }
    __syncthreads();
  }

  float4* __restrict__ S4 = (float4*)Sp + (size_t)h * (NN * NQ);
  #pragma unroll
  for (int r = 0; r < 4; ++r)
    S4[(i0 + w * 4 + r) * NQ + jq0 + ln] =
        make_float4(acc[r][0], acc[r][1], acc[r][2], acc[r][3]);
}

// 256 blocks x 4 rows, one wave per row. Row stats: pure wave shuffles, no
// barriers. Col partials over the 4-row stripe: one LDS merge + 1 barrier.
__global__ __launch_bounds__(256)
void sumstats_kernel(const float* __restrict__ Sp,
                     float* __restrict__ rmax, float* __restrict__ rsum,
                     float* __restrict__ pm, float* __restrict__ ps) {
  __shared__ float sm[4][NN];       // 16 KB: s values (-dist) per row
  const int t  = threadIdx.x;
  const int w  = t >> 6;            // wave = local row
  const int ln = t & 63;
  const int row = blockIdx.x * 4 + w;
  const float4* A = (const float4*)Sp + (size_t)row * NQ;
  const float4* B = A + (size_t)NN * NQ;

  float4 v[4];
  #pragma unroll
  for (int k = 0; k < 4; ++k) {
    const int c = ln + k * 64;
    const float4 a = A[c];
    const float4 b = B[c];
    v[k] = make_float4(-(a.x + b.x), -(a.y + b.y), -(a.z + b.z), -(a.w + b.w));
    ((float4*)sm[w])[c] = v[k];     // s values to LDS for the column merge
  }
  float m = -1e30f;
  #pragma unroll
  for (int k = 0; k < 4; ++k)
    m = fmaxf(m, fmaxf(fmaxf(v[k].x, v[k].y), fmaxf(v[k].z, v[k].w)));
  m = waveMax(m);
  float l = 0.f;
  #pragma unroll
  for (int k = 0; k < 4; ++k)
    l += __expf(v[k].x - m) + __expf(v[k].y - m) +
         __expf(v[k].z - m) + __expf(v[k].w - m);
  l = waveSum(l);
  if (ln == 0) { rmax[row] = m; rsum[row] = l; }

  __syncthreads();
  // column merge: 256 threads x 4 cols (float4)
  const float4 s0 = ((const float4*)sm[0])[t];
  const float4 s1 = ((const float4*)sm[1])[t];
  const float4 s2 = ((const float4*)sm[2])[t];
  const float4 s3 = ((const float4*)sm[3])[t];
  float4 M, L;
  M.x = fmaxf(fmaxf(s0.x, s1.x), fmaxf(s2.x, s3.x));
  M.y = fmaxf(fmaxf(s0.y, s1.y), fmaxf(s2.y, s3.y));
  M.z = fmaxf(fmaxf(s0.z, s1.z), fmaxf(s2.z, s3.z));
  M.w = fmaxf(fmaxf(s0.w, s1.w), fmaxf(s2.w, s3.w));
  L.x = __expf(s0.x - M.x) + __expf(s1.x - M.x) + __expf(s2.x - M.x) + __expf(s3.x - M.x);
  L.y = __expf(s0.y - M.y) + __expf(s1.y - M.y) + __expf(s2.y - M.y) + __expf(s3.y - M.y);
  L.z = __expf(s0.z - M.z) + __expf(s1.z - M.z) + __expf(s2.z - M.z) + __expf(s3.z - M.z);
  L.w = __expf(s0.w - M.w) + __expf(s1.w - M.w) + __expf(s2.w - M.w) + __expf(s3.w - M.w);
  ((float4*)pm)[blockIdx.x * NQ + t] = M;
  ((float4*)ps)[blockIdx.x * NQ + t] = L;
}

// 32 blocks x 32 cols: fold the 256 stripes, j-fastest (coalesced 128 B
// segments). 8 groups x 32 stripes each, LDS-merged.
__global__ __launch_bounds__(256)
void colcombine_kernel(const float* __restrict__ pm, const float* __restrict__ ps,
                       float* __restrict__ cmax, float* __restrict__ csum,
                       float* __restrict__ accum) {
  __shared__ float sm[8][32], sl[8][32];
  const int b = blockIdx.x, t = threadIdx.x;
  if (b == 0 && t == 0) {
    accum[0] = 0.f; accum[1] = 0.f; ((unsigned int*)accum)[2] = 0u;
  }
  const int jl = t & 31;
  const int g  = t >> 5;            // fold group 0..7 (32 stripes each)
  const int j  = b * 32 + jl;
  float m = -1e30f;
  #pragma unroll 8
  for (int k = 0; k < 32; ++k) m = fmaxf(m, pm[(g * 32 + k) * NN + j]);
  float l = 0.f;
  #pragma unroll 8
  for (int k = 0; k < 32; ++k)
    l += __expf(pm[(g * 32 + k) * NN + j] - m) * ps[(g * 32 + k) * NN + j];
  sm[g][jl] = m; sl[g][jl] = l;
  __syncthreads();
  if (g == 0) {
    float M = sm[0][jl];
    #pragma unroll
    for (int k = 1; k < 8; ++k) M = fmaxf(M, sm[k][jl]);
    float L = 0.f;
    #pragma unroll
    for (int k = 0; k < 8; ++k) L += sl[k][jl] * __expf(sm[k][jl] - M);
    cmax[j] = M; csum[j] = L;
  }
}

// 512 blocks x 2 rows: v = slab0+slab1, u = a+b-a*b, reduce, atomic;
// LAST block divides.
__global__ __launch_bounds__(256)
void final_kernel(const float* __restrict__ Sp,
                  const float* __restrict__ rmax, const float* __restrict__ rsum,
                  const float* __restrict__ cmax, const float* __restrict__ csum,
                  float* __restrict__ accum, float* __restrict__ out) {
  __shared__ float redn[4], redd[4];
  const int t = threadIdx.x;
  const int row0 = blockIdx.x * 2;
  const float4* A = (const float4*)Sp;
  const float4* B = A + (size_t)NN * NQ;
  const float4 cm = ((const float4*)cmax)[t];
  const float4 cs = ((const float4*)csum)[t];
  float un = 0.f, ud = 0.f;
  #pragma unroll
  for (int r = 0; r < 2; ++r) {
    const int row = row0 + r;
    const float rm = rmax[row];
    const float ri = 1.f / rsum[row];
    const float4 pa = A[row * NQ + t];
    const float4 pb = B[row * NQ + t];
    const float4 p = make_float4(pa.x + pb.x, pa.y + pb.y, pa.z + pb.z, pa.w + pb.w);
    {
      const float s = -p.x;
      const float a = __expf(s - rm) * ri;
      const float b = __expf(s - cm.x) / cs.x;
      const float u = a + b - a * b;
      un += u * s; ud += u;
    }
    {
      const float s = -p.y;
      const float a = __expf(s - rm) * ri;
      const float b = __expf(s - cm.y) / cs.y;
      const float u = a + b - a * b;
      un += u * s; ud += u;
    }
    {
      const float s = -p.z;
      const float a = __expf(s - rm) * ri;
      const float b = __expf(s - cm.z) / cs.z;
      const float u = a + b - a * b;
      un += u * s; ud += u;
    }
    {
      const float s = -p.w;
      const float a = __expf(s - rm) * ri;
      const float b = __expf(s - cm.w) / cs.w;
      const float u = a + b - a * b;
      un += u * s; ud += u;
    }
  }
  un = waveSum(un); ud = waveSum(ud);
  if ((t & 63) == 0) { redn[t >> 6] = un; redd[t >> 6] = ud; }
  __syncthreads();
  if (t == 0) {
    atomicAdd(&accum[0], redn[0] + redn[1] + redn[2] + redn[3]);
    atomicAdd(&accum[1], redd[0] + redd[1] + redd[2] + redd[3]);
    __threadfence();
    unsigned int* cnt = (unsigned int*)accum + 2;
    const unsigned int old = atomicAdd(cnt, 1u);
    if (old == gridDim.x - 1) {
      const float n = atomicAdd(&accum[0], 0.f);
      const float d = atomicAdd(&accum[1], 0.f);
      out[0] = n / d;
    }
  }
}

// ---------------- fallback path (R2, ws >= ~148 KB, proven) ----------------

#define TJ  128
#define NCH (NN / TJ)
#define BLK 256

__global__ __launch_bounds__(BLK)
void stats2_kernel(const float* __restrict__ zx, const float* __restrict__ zy,
                   float* __restrict__ partM, float* __restrict__ partS) {
  const int side = blockIdx.z;
  const float* __restrict__ X = side ? zy : zx;
  const float* __restrict__ Y = side ? zx : zy;
  const int j0 = blockIdx.x * TJ;
  const int i0 = blockIdx.y * 8;
  const int t  = threadIdx.x;
  const int rg = t >> 5;
  const int c  = t & 31;

  __shared__ float xs[8 * DD];
  for (int k = t; k < 8 * DD; k += BLK)
    xs[k] = X[(k >> 3) * NN + i0 + (k & 7)];
  __syncthreads();

  const float4* __restrict__ Y4 = (const float4*)Y;
  const int yb = (j0 >> 2) + c;
  float4 acc = make_float4(0.f, 0.f, 0.f, 0.f);
  #pragma unroll 8
  for (int d = 0; d < DD; ++d) {
    const float4 yv = Y4[d * NQ + yb];
    const float xv = xs[d * 8 + rg];
    acc.x += fabsf(xv - yv.x);
    acc.y += fabsf(xv - yv.y);
    acc.z += fabsf(xv - yv.z);
    acc.w += fabsf(xv - yv.w);
  }

  float m = fmaxf(fmaxf(-acc.x, -acc.y), fmaxf(-acc.z, -acc.w));
  #pragma unroll
  for (int off = 16; off > 0; off >>= 1) m = fmaxf(m, __shfl_xor(m, off, 32));
  float p = __expf(-acc.x - m) + __expf(-acc.y - m) +
            __expf(-acc.z - m) + __expf(-acc.w - m);
  #pragma unroll
  for (int off = 16; off > 0; off >>= 1) p += __shfl_xor(p, off, 32);

  if (c == 0) {
    const int idx = side * (NCH * NN) + blockIdx.x * NN + (i0 + rg);
    partM[idx] = m;
    partS[idx] = p;
  }
}

__global__ __launch_bounds__(BLK)
void combine_kernel_fb(const float* __restrict__ partM, const float* __restrict__ partS,
                       float* __restrict__ rmax, float* __restrict__ rsum,
                       float* __restrict__ cmax, float* __restrict__ csum,
                       float* __restrict__ accum) {
  const int gid = blockIdx.x * BLK + threadIdx.x;
  if (gid == 0) { accum[0] = 0.f; accum[1] = 0.f; }
  const int sd = gid >> 10;
  const int i  = gid & (NN - 1);
  float mk[NCH], sk[NCH];
  #pragma unroll
  for (int k = 0; k < NCH; ++k) {
    mk[k] = partM[sd * (NCH * NN) + k * NN + i];
    sk[k] = partS[sd * (NCH * NN) + k * NN + i];
  }
  float m = mk[0];
  #pragma unroll
  for (int k = 1; k < NCH; ++k) m = fmaxf(m, mk[k]);
  float s = 0.f;
  #pragma unroll
  for (int k = 0; k < NCH; ++k) s += __expf(mk[k] - m) * sk[k];
  if (sd == 0) { rmax[i] = m; rsum[i] = s; }
  else         { cmax[i] = m; csum[i] = s; }
}

__global__ __launch_bounds__(BLK)
void final2_kernel(const float* __restrict__ zx, const float* __restrict__ zy,
                   const float* __restrict__ rmax, const float* __restrict__ rsum,
                   const float* __restrict__ cmax, const float* __restrict__ csum,
                   float* __restrict__ accum) {
  const int j0 = blockIdx.x * TJ;
  const int i0 = blockIdx.y * 8;
  const int t  = threadIdx.x;
  const int rg = t >> 5;
  const int c  = t & 31;

  __shared__ float xs[8 * DD];
  __shared__ float redn[4], redd[4];
  for (int k = t; k < 8 * DD; k += BLK)
    xs[k] = zx[(k >> 3) * NN + i0 + (k & 7)];
  __syncthreads();

  const float4* __restrict__ Y4 = (const float4*)zy;
  const int yb = (j0 >> 2) + c;
  float4 acc = make_float4(0.f, 0.f, 0.f, 0.f);
  #pragma unroll 8
  for (int d = 0; d < DD; ++d) {
    const float4 yv = Y4[d * NQ + yb];
    const float xv = xs[d * 8 + rg];
    acc.x += fabsf(xv - yv.x);
    acc.y += fabsf(xv - yv.y);
    acc.z += fabsf(xv - yv.z);
    acc.w += fabsf(xv - yv.w);
  }

  const int i = i0 + rg;
  const float rm = rmax[i];
  const float ri = 1.f / rsum[i];
  const float4 cm = ((const float4*)cmax)[yb];
  const float4 cs = ((const float4*)csum)[yb];

  float un = 0.f, ud = 0.f;
  {
    const float s = -acc.x;
    const float a = __expf(s - rm) * ri;
    const float b = __expf(s - cm.x) / cs.x;
    const float u = a + b - a * b;
    un += u * s; ud += u;
  }
  {
    const float s = -acc.y;
    const float a = __expf(s - rm) * ri;
    const float b = __expf(s - cm.y) / cs.y;
    const float u = a + b - a * b;
    un += u * s; ud += u;
  }
  {
    const float s = -acc.z;
    const float a = __expf(s - rm) * ri;
    const float b = __expf(s - cm.z) / cs.z;
    const float u = a + b - a * b;
    un += u * s; ud += u;
  }
  {
    const float s = -acc.w;
    const float a = __expf(s - rm) * ri;
    const float b = __expf(s - cm.w) / cs.w;
    const float u = a + b - a * b;
    un += u * s; ud += u;
  }

  un = waveSum(un); ud = waveSum(ud);
  if ((t & 63) == 0) { redn[t >> 6] = un; redd[t >> 6] = ud; }
  __syncthreads();
  if (t == 0) {
    atomicAdd(&accum[0], redn[0] + redn[1] + redn[2] + redn[3]);
    atomicAdd(&accum[1], redd[0] + redd[1] + redd[2] + redd[3]);
  }
}

__global__ void finalize_kernel(const float* __restrict__ accum, float* __restrict__ out) {
  out[0] = accum[0] / accum[1];
}

// ---------------------------------------------------------------------------

extern "C" void kernel_launch(void* const* d_in, const int* in_sizes, int n_in,
                              void* d_out, int out_size, void* d_ws, size_t ws_size,
                              hipStream_t stream) {
  const float* zx = (const float*)d_in[0];   // (1, D, N): X[d*N + i]
  const float* zy = (const float*)d_in[1];   // (1, D, M): Y[d*M + j]
  float* ws  = (float*)d_ws;
  float* out = (float*)d_out;

  // fast-path ws layout (floats): ~10.6 MB
  float* accum = ws;                         // [0]=num, [1]=den, [2]=ticket
  float* Sp    = ws + 16;                    // 2 slabs x 1M floats (8 MB)
  float* pm    = Sp + 2 * NN * NN;           // 256 * 1024
  float* ps    = pm + 256 * NN;              // 256 * 1024
  float* rmax  = ps + 256 * NN;
  float* rsum  = rmax + NN;
  float* cmax  = rsum + NN;
  float* csum  = cmax + NN;
  const size_t need = (size_t)((csum + NN) - ws) * sizeof(float);

  if (ws_size >= need) {
    dim3 g1(4, 64, 2);                       // 512 blocks
    scompute_kernel<<<g1, 256, 0, stream>>>(zx, zy, Sp);
    sumstats_kernel<<<NN / 4, 256, 0, stream>>>(Sp, rmax, rsum, pm, ps);
    colcombine_kernel<<<32, 256, 0, stream>>>(pm, ps, cmax, csum, accum);
    final_kernel<<<NN / 2, 256, 0, stream>>>(Sp, rmax, rsum, cmax, csum, accum, out);
  } else {
    // R2 fallback (~148 KB)
    float* partM = ws + 16;
    float* partS = partM + 2 * NCH * NN;
    float* frmax = partS + 2 * NCH * NN;
    float* frsum = frmax + NN;
    float* fcmax = frsum + NN;
    float* fcsum = fcmax + NN;
    dim3 sgrid(NCH, NN / 8, 2);
    stats2_kernel<<<sgrid, BLK, 0, stream>>>(zx, zy, partM, partS);
    combine_kernel_fb<<<(2 * NN) / BLK, BLK, 0, stream>>>(partM, partS,
                                                          frmax, frsum, fcmax, fcsum, accum);
    dim3 fgrid(NCH, NN / 8);
    final2_kernel<<<fgrid, BLK, 0, stream>>>(zx, zy, frmax, frsum, fcmax, fcsum, accum);
    finalize_kernel<<<1, 1, 0, stream>>>(accum, out);
  }
}